// Round 5
// baseline (307.245 us; speedup 1.0000x reference)
//
#include <hip/hip_runtime.h>

// Problem constants (from reference): B=8, C=3, H=512, W=512
constexpr int Cc = 3;
constexpr int Hc = 512;
constexpr int Wc = 512;
constexpr int HW = Hc * Wc;              // 262144 = 2^18
constexpr int NPIX = 8 * HW;             // 2097152
constexpr int TPB  = 256;
constexpr int PPT  = 4;                  // pixels per thread
constexpr int PPB  = TPB * PPT;          // 1024 pixels per block
constexpr int NBLK = NPIX / PPB;         // 2048 blocks
constexpr int SIG4_PER_BLK = PPB * 9 / 4;  // 2304 float4 (36 KB) of sigma per block

// ws layout: [0, NBLK) doubles = per-block partial sums
//            then NBLK floats  = per-block partial maxes
//            then 1 uint       = ticket counter (NO init required — see mod trick)

__global__ __launch_bounds__(256, 4) void map_loss_main(
    const float* __restrict__ target,
    const float* __restrict__ mu,
    const float* __restrict__ sigma_y,
    double* __restrict__ part_sum,
    float* __restrict__ part_max,
    unsigned int* __restrict__ ticket,
    float* __restrict__ out)
{
    // 36 KB sigma staging buffer; swizzled layout: lds4[s] holds global f4 (s ^ ((s>>6)&7))
    __shared__ float4 lds4[SIG4_PER_BLK];

    const int tid = threadIdx.x;
    const int bid = blockIdx.x;

    // ---- per-thread residual loads (per-instruction coalesced) ----
    const int g = bid * TPB + tid;           // 4-pixel group index
    const long long p0 = (long long)g << 2;
    const int b  = (int)(p0 >> 18);
    const int hw = (int)p0 & (HW - 1);
    const long long base = (long long)b * (Cc * HW) + hw;

    const float4* tg = (const float4*)(target + base);
    const float4* mm = (const float4*)(mu + base);
    float4 d0 = tg[0];        float4 m0 = mm[0];
    float4 d1 = tg[HW / 4];   float4 m1 = mm[HW / 4];
    float4 d2 = tg[HW / 2];   float4 m2 = mm[HW / 2];

    // ---- cooperative sigma staging: block slab = float4 [bid*2304, +2304) ----
    // Linear LDS dest (global_load_lds requirement); source index pre-swizzled
    // by s ^ ((s>>6)&7) — XOR term is wave-uniform per instruction, so each
    // instruction reads a contiguous permuted 1KB block: fully coalesced.
    const float4* sblk = (const float4*)sigma_y + (long long)bid * SIG4_PER_BLK;
    const int w = tid >> 6;
    #pragma unroll
    for (int j = 0; j < 9; ++j) {
        const int s = j * TPB + tid;         // linear dest slot
        const int c = (s >> 6) & 7;          // wave-uniform swizzle term
        __builtin_amdgcn_global_load_lds(
            (const __attribute__((address_space(1))) void*)(sblk + (s ^ c)),
            (__attribute__((address_space(3))) void*)(&lds4[j * TPB + w * 64]),
            16, 0, 0);
    }
    __syncthreads();                         // drains vmcnt (covers tg/mm loads too)

    // residuals
    d0.x -= m0.x; d0.y -= m0.y; d0.z -= m0.z; d0.w -= m0.w;
    d1.x -= m1.x; d1.y -= m1.y; d1.z -= m1.z; d1.w -= m1.w;
    d2.x -= m2.x; d2.y -= m2.y; d2.z -= m2.z; d2.w -= m2.w;

    // ---- swizzled LDS read: thread t's 144 B = slots 9t..9t+8 (<=2-way, free) ----
    union { float4 v[9]; float f[36]; } S;
    #pragma unroll
    for (int k = 0; k < 9; ++k) {
        const int r = 9 * tid + k;
        const int x = r ^ ((r >> 6) & 7);
        S.v[k] = lds4[x];
    }

    double local_sum = 0.0;
    float local_max = 0.0f;

    const float T0[4] = {d0.x, d0.y, d0.z, d0.w};
    const float T1[4] = {d1.x, d1.y, d1.z, d1.w};
    const float T2[4] = {d2.x, d2.y, d2.z, d2.w};

    #pragma unroll
    for (int i = 0; i < 4; ++i) {
        const float* s = S.f + i * 9;
        float s00 = s[0], s01 = s[1], s02 = s[2];
        float s11 = s[4], s12 = s[5], s22 = s[8];

        // adjugate (symmetric)
        float a00 = s11 * s22 - s12 * s12;
        float a01 = s02 * s12 - s01 * s22;
        float a02 = s01 * s12 - s02 * s11;
        float a11 = s00 * s22 - s02 * s02;
        float a12 = s01 * s02 - s00 * s12;
        float a22 = s00 * s11 - s01 * s01;

        float det = s00 * a00 + s01 * a01 + s02 * a02;

        float t0 = T0[i], t1 = T1[i], t2 = T2[i];
        float quad = t0 * t0 * a00 + t1 * t1 * a11 + t2 * t2 * a22
                   + 2.0f * (t0 * t1 * a01 + t0 * t2 * a02 + t1 * t2 * a12);

        float t1term = 0.5f * quad / det;
        float t2term = 0.5f * logf(det);

        local_sum += (double)(t1term + t2term);
        local_max = fmaxf(local_max, t1term);
    }

    // ---- block reduction (deterministic) ----
    for (int off = 32; off > 0; off >>= 1) {
        local_sum += __shfl_down(local_sum, off, 64);
        local_max = fmaxf(local_max, __shfl_down(local_max, off, 64));
    }

    __shared__ double ssum[4];
    __shared__ float  smax[4];
    __shared__ int    is_last;
    const int lane = tid & 63;
    if (lane == 0) { ssum[w] = local_sum; smax[w] = local_max; }
    __syncthreads();

    if (tid == 0) {
        part_sum[bid] = ssum[0] + ssum[1] + ssum[2] + ssum[3];
        part_max[bid] = fmaxf(fmaxf(smax[0], smax[1]), fmaxf(smax[2], smax[3]));
        // release partials, then take a ticket (device-scope atomic).
        __threadfence();
        unsigned int old = atomicAdd(ticket, 1u);
        // mod trick: for ANY initial counter value, exactly one of this
        // launch's NBLK increments satisfies old % NBLK == NBLK-1 -> that
        // block is the last to arrive. No ws init, replay-safe.
        is_last = ((old & (unsigned)(NBLK - 1)) == (unsigned)(NBLK - 1)) ? 1 : 0;
    }
    __syncthreads();

    if (is_last) {
        // ---- inline finalize: identical tree to the old second kernel ----
        __threadfence();                       // acquire partials
        double s = 0.0;
        float m = 0.0f;
        for (int i = tid; i < NBLK; i += TPB) {
            s += part_sum[i];
            m = fmaxf(m, part_max[i]);
        }
        for (int off = 32; off > 0; off >>= 1) {
            s += __shfl_down(s, off, 64);
            m = fmaxf(m, __shfl_down(m, off, 64));
        }
        if (lane == 0) { ssum[w] = s; smax[w] = m; }
        __syncthreads();
        if (tid == 0) {
            double bs = ssum[0] + ssum[1] + ssum[2] + ssum[3];
            float  bm = fmaxf(fmaxf(smax[0], smax[1]), fmaxf(smax[2], smax[3]));
            out[0] = (bm > 1e8f) ? 0.0f : (float)(bs / (double)NPIX);
        }
    }
}

extern "C" void kernel_launch(void* const* d_in, const int* in_sizes, int n_in,
                              void* d_out, int out_size, void* d_ws, size_t ws_size,
                              hipStream_t stream) {
    const float* target  = (const float*)d_in[0];
    const float* mu      = (const float*)d_in[1];
    // d_in[2] = sigma_mu (unused), d_in[3] = sigma_n (unused)
    const float* sigma_y = (const float*)d_in[4];
    float* out = (float*)d_out;

    double* part_sum = (double*)d_ws;
    float*  part_max = (float*)((char*)d_ws + NBLK * sizeof(double));
    unsigned int* ticket = (unsigned int*)((char*)d_ws + NBLK * (sizeof(double) + sizeof(float)));
    // partials: every slot written unconditionally by its block.
    // ticket: needs NO initialization (mod-NBLK last-arrival trick).

    map_loss_main<<<NBLK, TPB, 0, stream>>>(target, mu, sigma_y,
                                            part_sum, part_max, ticket, out);
}

// Round 6
// 215.866 us; speedup vs baseline: 1.4233x; 1.4233x over previous
//
#include <hip/hip_runtime.h>

// Problem constants (from reference): B=8, C=3, H=512, W=512
constexpr int Cc = 3;
constexpr int Hc = 512;
constexpr int Wc = 512;
constexpr int HW = Hc * Wc;              // 262144 = 2^18
constexpr int NPIX = 8 * HW;             // 2097152
constexpr int TPB  = 256;
constexpr int PPT  = 4;                  // pixels per thread
constexpr int PPB  = TPB * PPT;          // 1024 pixels per block
constexpr int NBLK = NPIX / PPB;         // 2048 blocks
constexpr int SIG4_PER_BLK = PPB * 9 / 4;  // 2304 float4 (36 KB) of sigma per block

// ws layout: [0, NBLK) doubles = per-block partial sums
//            then NBLK floats  = per-block partial maxes

__global__ __launch_bounds__(256, 4) void map_loss_main(
    const float* __restrict__ target,
    const float* __restrict__ mu,
    const float* __restrict__ sigma_y,
    double* __restrict__ part_sum,
    float* __restrict__ part_max)
{
    // 36 KB sigma staging; layout identical to the verified round-2 kernel:
    // lds4[s ^ ((s>>6)&7)] holds global float4 slot s of this block's slab.
    __shared__ float4 lds4[SIG4_PER_BLK];

    const int tid = threadIdx.x;
    const int bid = blockIdx.x;

    // ---- issue ALL 15 loads to REGISTERS, every one coalesced ----
    // (no global_load_lds anywhere: tests the LDS-DMA-throughput hypothesis)
    const int g = bid * TPB + tid;           // 4-pixel group index
    const long long p0 = (long long)g << 2;
    const int b  = (int)(p0 >> 18);
    const int hw = (int)p0 & (HW - 1);
    const long long base = (long long)b * (Cc * HW) + hw;

    // sigma: 9 linear coalesced wave-loads of this block's contiguous slab
    const float4* sblk = (const float4*)sigma_y + (long long)bid * SIG4_PER_BLK;
    float4 sv0 = sblk[0 * TPB + tid];
    float4 sv1 = sblk[1 * TPB + tid];
    float4 sv2 = sblk[2 * TPB + tid];
    float4 sv3 = sblk[3 * TPB + tid];
    float4 sv4 = sblk[4 * TPB + tid];
    float4 sv5 = sblk[5 * TPB + tid];
    float4 sv6 = sblk[6 * TPB + tid];
    float4 sv7 = sblk[7 * TPB + tid];
    float4 sv8 = sblk[8 * TPB + tid];

    const float4* tg = (const float4*)(target + base);
    const float4* mm = (const float4*)(mu + base);
    float4 d0 = tg[0];        float4 m0 = mm[0];
    float4 d1 = tg[HW / 4];   float4 m1 = mm[HW / 4];
    float4 d2 = tg[HW / 2];   float4 m2 = mm[HW / 2];

    // ---- scatter sigma to LDS with the XOR swizzle on the WRITE address ----
    // s = j*256+tid; addr = s ^ c with c=(s>>6)&7 (c untouched by the XOR, so
    // read side r ^ ((r>>6)&7) recovers exactly slot r — same involution the
    // round-2 kernel verified bit-exact). Per instruction the 64 written slots
    // are a bank-uniform permuted contiguous block: conflict-free.
    {
        float4* dst = lds4;
        #define SIG_STORE(J, V) do {                                   \
            const int s_ = (J) * TPB + tid;                            \
            dst[s_ ^ ((s_ >> 6) & 7)] = (V);                           \
        } while (0)
        SIG_STORE(0, sv0); SIG_STORE(1, sv1); SIG_STORE(2, sv2);
        SIG_STORE(3, sv3); SIG_STORE(4, sv4); SIG_STORE(5, sv5);
        SIG_STORE(6, sv6); SIG_STORE(7, sv7); SIG_STORE(8, sv8);
        #undef SIG_STORE
    }
    __syncthreads();

    // residuals (tg/mm regs; waits folded into first use)
    d0.x -= m0.x; d0.y -= m0.y; d0.z -= m0.z; d0.w -= m0.w;
    d1.x -= m1.x; d1.y -= m1.y; d1.z -= m1.z; d1.w -= m1.w;
    d2.x -= m2.x; d2.y -= m2.y; d2.z -= m2.z; d2.w -= m2.w;

    // ---- swizzled LDS read: thread t's 144 B = slots 9t..9t+8 (<=2-way, free) ----
    union { float4 v[9]; float f[36]; } S;
    #pragma unroll
    for (int k = 0; k < 9; ++k) {
        const int r = 9 * tid + k;
        const int x = r ^ ((r >> 6) & 7);
        S.v[k] = lds4[x];
    }

    double local_sum = 0.0;
    float local_max = 0.0f;

    const float T0[4] = {d0.x, d0.y, d0.z, d0.w};
    const float T1[4] = {d1.x, d1.y, d1.z, d1.w};
    const float T2[4] = {d2.x, d2.y, d2.z, d2.w};

    #pragma unroll
    for (int i = 0; i < 4; ++i) {
        const float* s = S.f + i * 9;
        float s00 = s[0], s01 = s[1], s02 = s[2];
        float s11 = s[4], s12 = s[5], s22 = s[8];

        // adjugate (symmetric)
        float a00 = s11 * s22 - s12 * s12;
        float a01 = s02 * s12 - s01 * s22;
        float a02 = s01 * s12 - s02 * s11;
        float a11 = s00 * s22 - s02 * s02;
        float a12 = s01 * s02 - s00 * s12;
        float a22 = s00 * s11 - s01 * s01;

        float det = s00 * a00 + s01 * a01 + s02 * a02;

        float t0 = T0[i], t1 = T1[i], t2 = T2[i];
        float quad = t0 * t0 * a00 + t1 * t1 * a11 + t2 * t2 * a22
                   + 2.0f * (t0 * t1 * a01 + t0 * t2 * a02 + t1 * t2 * a12);

        float t1term = 0.5f * quad / det;
        float t2term = 0.5f * logf(det);

        local_sum += (double)(t1term + t2term);
        local_max = fmaxf(local_max, t1term);
    }

    // ---- block reduction (deterministic; identical tree to round 2) ----
    for (int off = 32; off > 0; off >>= 1) {
        local_sum += __shfl_down(local_sum, off, 64);
        local_max = fmaxf(local_max, __shfl_down(local_max, off, 64));
    }

    __shared__ double ssum[4];
    __shared__ float  smax[4];
    const int w = tid >> 6;
    const int lane = tid & 63;
    if (lane == 0) { ssum[w] = local_sum; smax[w] = local_max; }
    __syncthreads();

    if (tid == 0) {
        part_sum[bid] = ssum[0] + ssum[1] + ssum[2] + ssum[3];
        part_max[bid] = fmaxf(fmaxf(smax[0], smax[1]), fmaxf(smax[2], smax[3]));
    }
}

__global__ __launch_bounds__(256) void map_loss_finalize(
    const double* __restrict__ part_sum,
    const float* __restrict__ part_max,
    float* __restrict__ out)
{
    double s = 0.0;
    float m = 0.0f;
    for (int i = threadIdx.x; i < NBLK; i += 256) {
        s += part_sum[i];
        m = fmaxf(m, part_max[i]);
    }

    for (int off = 32; off > 0; off >>= 1) {
        s += __shfl_down(s, off, 64);
        m = fmaxf(m, __shfl_down(m, off, 64));
    }

    __shared__ double ssum[4];
    __shared__ float  smax[4];
    int wave = threadIdx.x >> 6;
    int lane = threadIdx.x & 63;
    if (lane == 0) { ssum[wave] = s; smax[wave] = m; }
    __syncthreads();

    if (threadIdx.x == 0) {
        double bs = ssum[0] + ssum[1] + ssum[2] + ssum[3];
        float  bm = fmaxf(fmaxf(smax[0], smax[1]), fmaxf(smax[2], smax[3]));
        out[0] = (bm > 1e8f) ? 0.0f : (float)(bs / (double)NPIX);
    }
}

extern "C" void kernel_launch(void* const* d_in, const int* in_sizes, int n_in,
                              void* d_out, int out_size, void* d_ws, size_t ws_size,
                              hipStream_t stream) {
    const float* target  = (const float*)d_in[0];
    const float* mu      = (const float*)d_in[1];
    // d_in[2] = sigma_mu (unused), d_in[3] = sigma_n (unused)
    const float* sigma_y = (const float*)d_in[4];
    float* out = (float*)d_out;

    double* part_sum = (double*)d_ws;
    float*  part_max = (float*)((char*)d_ws + NBLK * sizeof(double));
    // every slot is written unconditionally by its block — no pre-zeroing needed

    map_loss_main<<<NBLK, TPB, 0, stream>>>(target, mu, sigma_y, part_sum, part_max);
    map_loss_finalize<<<1, 256, 0, stream>>>(part_sum, part_max, out);
}